// Round 7
// baseline (359.736 us; speedup 1.0000x reference)
//
#include <hip/hip_runtime.h>

// Problem constants: BOX=256, OS=1 -> S=256, NC=10, B=16, N=262144
#define S_     256
#define NC_    10
#define TS     32           // scatter tile size (32x32 px)
#define NBIN2  64           // 8x8 tiles of 32px per batch
#define CAPR   4608         // record slab per tile (mean 4096, +8 sigma)
#define IW     33           // LDS image width (32+1 for dx/dy=1 spill)
#define IMSZ   (NC_ * IW * IW)   // 10890 words = 43.6 KB
#define FPSCALE 262144.0f        // 2^18 fixed-point scale for LDS s32 accum
#define FPINV   (1.0f / 262144.0f)
#define WPTS   512          // points per wave (8 per lane)
#define LPW    8

typedef unsigned int u32;
typedef float f32x4 __attribute__((ext_vector_type(4)));

__device__ __forceinline__ u32 f2bf(float f) {          // f32 -> bf16 (RNE)
    u32 u = __float_as_uint(f);
    return (u + 0x7fffu + ((u >> 16) & 1u)) >> 16;
}
__device__ __forceinline__ float bf2f(u32 h) { return __uint_as_float(h << 16); }

// Record (24 B, 3x uint2): w0 = qx | qy<<16 (tile-local coords, fp 1/2048 px);
// w1..w5 = 10 bf16 values.
//
// R7: k_scatter is WAVE-SYNCHRONOUS (R2/R5/R6 lesson: four structural attacks
// all stuck at ~100-112us with nothing >35% utilized -> the 4-barrier phase
// structure was the serializer). Each wave: private 64 counters + private
// 12.75KB LDS staging, own shfl-scan, own global slab claim, own flush.
// ZERO __syncthreads. 12 independent wave-pipelines/CU.

// ---- K3: per-wave counting sort + coalesced record flush ----
__global__ void __launch_bounds__(256)
k_scatter(const float* __restrict__ points, const float* __restrict__ values,
          u32* __restrict__ cursor, u32* __restrict__ ovfCnt,
          u32* __restrict__ ovfBuf, uint2* __restrict__ recs, int N) {
    __shared__ u32 cnt[4][NBIN2];            // per-wave histogram -> cursor
    __shared__ unsigned char binId[4][WPTS]; // per-wave bin of sorted slot
    __shared__ u32 lw[4][6][WPTS];           // per-wave 12KB sorted words

    const int tid = threadIdx.x;
    const int wid = tid >> 6, lane = tid & 63;
    const int wpb = N / (4 * WPTS);          // block-chunks per batch (128)
    const int b  = blockIdx.x / wpb;
    const int n0 = (blockIdx.x % wpb) * (4 * WPTS) + wid * WPTS + lane * LPW;
    const float* pb = points + (size_t)b * 2 * N;
    const float* vb = values + (size_t)b * NC_ * N;

    // 24 float4 loads (8 consecutive points/lane; pairs of f32x4 per stream)
    f32x4 px[2], py[2], vv[NC_][2];
    px[0] = *(const f32x4*)(pb + n0);
    px[1] = *(const f32x4*)(pb + n0 + 4);
    py[0] = *(const f32x4*)(pb + (size_t)N + n0);
    py[1] = *(const f32x4*)(pb + (size_t)N + n0 + 4);
#pragma unroll
    for (int c = 0; c < NC_; ++c) {
        vv[c][0] = *(const f32x4*)(vb + (size_t)c * N + n0);
        vv[c][1] = *(const f32x4*)(vb + (size_t)c * N + n0 + 4);
    }

    // wave-local phase boundaries are lgkmcnt waits, not block barriers
    cnt[wid][lane] = 0;
    asm volatile("s_waitcnt lgkmcnt(0)" ::: "memory");
    __builtin_amdgcn_sched_barrier(0);

    // phase 1: quantize 8 points, per-wave 64-bin histogram
    u32 w0[LPW], bn[LPW];
#pragma unroll
    for (int k = 0; k < LPW; ++k) {
        float pxx = (px[k >> 2][k & 3] + 0.5f) * (float)S_;
        float pyy = (py[k >> 2][k & 3] + 0.5f) * (float)S_;
        int xi = (int)floorf(pxx), yi = (int)floorf(pyy);
        u32 qx = __float2uint_rn((pxx - (float)(xi & ~31)) * 2048.0f);
        u32 qy = __float2uint_rn((pyy - (float)(yi & ~31)) * 2048.0f);
        qx = min(qx, 65535u); qy = min(qy, 65535u);
        w0[k] = qx | (qy << 16);
        bn[k] = (u32)(((yi >> 5) << 3) + (xi >> 5));
        atomicAdd(&cnt[wid][bn[k]], 1u);
    }
    asm volatile("s_waitcnt lgkmcnt(0)" ::: "memory");
    __builtin_amdgcn_sched_barrier(0);

    // phase 2: wave shfl exclusive scan + per-wave global slab claim.
    // gOff lives in lane==bin's register; pack/flush fetch it via shfl.
    u32 myCnt = cnt[wid][lane];
    u32 x = myCnt;
#pragma unroll
    for (int off = 1; off < 64; off <<= 1) {
        u32 y = __shfl_up(x, off, 64);
        if (lane >= off) x += y;
    }
    u32 excl = x - myCnt;
    const u32 gt = (u32)b * NBIN2 + (u32)lane;
    u32 gOffReg = 0;
    if (myCnt) gOffReg = gt * (u32)CAPR + atomicAdd(&cursor[gt], myCnt);
    gOffReg -= excl;
    cnt[wid][lane] = excl;               // becomes the wave's sort cursor
    asm volatile("s_waitcnt lgkmcnt(0)" ::: "memory");
    __builtin_amdgcn_sched_barrier(0);

    // phase 3: pack records, scatter into this wave's LDS region in bin order
#pragma unroll
    for (int k = 0; k < LPW; ++k) {
        u32 bin = bn[k];
        u32 slot = atomicAdd(&cnt[wid][bin], 1u);
        binId[wid][slot] = (unsigned char)bin;
        const int h = k >> 2, l = k & 3;
        lw[wid][0][slot] = w0[k];
        lw[wid][1][slot] = f2bf(vv[0][h][l]) | (f2bf(vv[1][h][l]) << 16);
        lw[wid][2][slot] = f2bf(vv[2][h][l]) | (f2bf(vv[3][h][l]) << 16);
        lw[wid][3][slot] = f2bf(vv[4][h][l]) | (f2bf(vv[5][h][l]) << 16);
        lw[wid][4][slot] = f2bf(vv[6][h][l]) | (f2bf(vv[7][h][l]) << 16);
        lw[wid][5][slot] = f2bf(vv[8][h][l]) | (f2bf(vv[9][h][l]) << 16);
    }
    asm volatile("s_waitcnt lgkmcnt(0)" ::: "memory");
    __builtin_amdgcn_sched_barrier(0);

    // phase 4: coalesced flush; consecutive lanes hold consecutive slots.
    const u32 tb0 = (u32)b * NBIN2;
#pragma unroll
    for (int k = 0; k < LPW; ++k) {
        u32 r = (u32)lane + (u32)k * 64;
        u32 bin = binId[wid][r];
        u32 dst = (u32)__shfl((int)gOffReg, (int)bin, 64) + r;
        u32 a0 = lw[wid][0][r], a1 = lw[wid][1][r], a2 = lw[wid][2][r],
            a3 = lw[wid][3][r], a4 = lw[wid][4][r], a5 = lw[wid][5][r];
        u32 rel = dst - (tb0 + bin) * (u32)CAPR;
        if (rel < (u32)CAPR) {           // true unless tile > CAPR records
            size_t s3 = (size_t)dst * 3;
            recs[s3]     = make_uint2(a0, a1);
            recs[s3 + 1] = make_uint2(a2, a3);
            recs[s3 + 2] = make_uint2(a4, a5);
        } else {                         // slab overflow -> side list
            u32 oi = atomicAdd(ovfCnt, 1u);
            u32* ob = ovfBuf + (size_t)oi * 7;
            ob[0] = tb0 + bin;
            ob[1] = a0; ob[2] = a1; ob[3] = a2;
            ob[4] = a3; ob[5] = a4; ob[6] = a5;
        }
    }
}

// ---- K4: LDS-image fixed-point deposit, one block per 32x32 tile ----
// Native ds_add_u32 (R4 lesson: f32 LDS atomicAdd = CAS loop, 8x slower).
// 2-deep register prefetch on the record stream.
__global__ void __launch_bounds__(256)
k_fused(const uint2* __restrict__ recs, const u32* __restrict__ cursor,
        float* __restrict__ out, float* __restrict__ borderBuf) {
    __shared__ u32 img[IMSZ];           // 43.6 KB -> 3 blocks/CU

    const int tid = threadIdx.x;
    const int g = blockIdx.x;                       // batch*64 + tile
    const int batch = g >> 6, t = g & 63;
    const int ox = (t & 7) * TS, oy = (t >> 3) * TS;
    const u32 base = (u32)g * (u32)CAPR;            // fixed slab base
    const u32 n = min(cursor[g], (u32)CAPR);        // overflow -> k_border tail

    for (int p = tid; p < IMSZ; p += 256) img[p] = 0u;
    __syncthreads();

    u32 i = tid;
    uint2 a0, a1, a2;
    if (i < n) {
        const uint2* rp = recs + (size_t)(base + i) * 3;
        a0 = rp[0]; a1 = rp[1]; a2 = rp[2];
    }
    while (i < n) {
        u32 j = i + 256;
        uint2 b0, b1, b2;
        if (j < n) {                     // prefetch next record
            const uint2* rp = recs + (size_t)(base + j) * 3;
            b0 = rp[0]; b1 = rp[1]; b2 = rp[2];
        }
        u32 qx = a0.x & 0xffffu, qy = a0.x >> 16;
        int xi = (int)(qx >> 11), yi = (int)(qy >> 11);
        float rx = (float)(qx & 2047u) * (1.0f / 2048.0f);
        float ry = (float)(qy & 2047u) * (1.0f / 2048.0f);
        float w00 = (1.0f - rx) * (1.0f - ry) * FPSCALE;   // (xi,   yi  )
        float w10 = rx * (1.0f - ry) * FPSCALE;            // (xi+1, yi  )
        float w01 = (1.0f - rx) * ry * FPSCALE;            // (xi,   yi+1)
        float w11 = rx * ry * FPSCALE;                     // (xi+1, yi+1)
        int p00 = yi * IW + xi;
        float v[NC_];
        v[0] = bf2f(a0.y & 0xffffu); v[1] = bf2f(a0.y >> 16);
        v[2] = bf2f(a1.x & 0xffffu); v[3] = bf2f(a1.x >> 16);
        v[4] = bf2f(a1.y & 0xffffu); v[5] = bf2f(a1.y >> 16);
        v[6] = bf2f(a2.x & 0xffffu); v[7] = bf2f(a2.x >> 16);
        v[8] = bf2f(a2.y & 0xffffu); v[9] = bf2f(a2.y >> 16);
#pragma unroll
        for (int c = 0; c < NC_; ++c) {
            float vc = v[c];
            u32* ib = img + c * (IW * IW) + p00;  // c*IW*IW*4 = imm offset
            atomicAdd(ib,          (u32)__float2int_rn(w00 * vc));
            atomicAdd(ib + 1,      (u32)__float2int_rn(w10 * vc));
            atomicAdd(ib + IW,     (u32)__float2int_rn(w01 * vc));
            atomicAdd(ib + IW + 1, (u32)__float2int_rn(w11 * vc));
        }
        a0 = b0; a1 = b1; a2 = b2;
        i = j;
    }
    __syncthreads();

    // writeback: interior (lx,ly in 1..31) owned uniquely by this tile
    for (int p = tid; p < IW * IW; p += 256) {
        int lx = p % IW, ly = p / IW;
        bool interior = (lx >= 1) & (lx <= 31) & (ly >= 1) & (ly <= 31);
        if (interior) {
            int gx = ox + lx, gy = oy + ly;
            float* ob = out + (size_t)batch * NC_ * S_ * S_ + gy * S_ + gx;
#pragma unroll
            for (int q = 0; q < NC_; ++q)
                ob[(size_t)q * S_ * S_] =
                    (float)(int)img[q * (IW * IW) + p] * FPINV;
        } else {
            float* bb = borderBuf + ((size_t)g * (IW * IW) + p) * NC_;
#pragma unroll
            for (int q = 0; q < NC_; ++q)
                bb[q] = (float)(int)img[q * (IW * IW) + p] * FPINV;
        }
    }
}

// ---- K5: combine border partials; tail blocks process slab-overflow list ----
// Border px per batch: 8 cols x 256 + 8 rows x 248 = 4032.
#define CLEAN_T 4096                                 // 16 tail blocks
__global__ void __launch_bounds__(256)
k_border(const float* __restrict__ borderBuf, float* __restrict__ out,
         const u32* __restrict__ ovfCnt, const u32* __restrict__ ovfBuf,
         int total) {
    int idx = blockIdx.x * 256 + threadIdx.x;
    if (idx >= total) {
        // overflow-cleanup role (no-op unless a tile exceeded CAPR records)
        u32 oc = *ovfCnt;
        for (u32 j = (u32)(idx - total); j < oc; j += CLEAN_T) {
            const u32* ob = ovfBuf + (size_t)j * 7;
            u32 g = ob[0];
            int batch = (int)(g >> 6), t = (int)(g & 63u);
            int ox = (t & 7) * TS, oy = (t >> 3) * TS;
            u32 w0 = ob[1];
            u32 qx = w0 & 0xffffu, qy = w0 >> 16;
            int xi = ox + (int)(qx >> 11), yi = oy + (int)(qy >> 11);
            float rx = (float)(qx & 2047u) * (1.0f / 2048.0f);
            float ry = (float)(qy & 2047u) * (1.0f / 2048.0f);
            float v[NC_];
            v[0] = bf2f(ob[2] & 0xffffu); v[1] = bf2f(ob[2] >> 16);
            v[2] = bf2f(ob[3] & 0xffffu); v[3] = bf2f(ob[3] >> 16);
            v[4] = bf2f(ob[4] & 0xffffu); v[5] = bf2f(ob[4] >> 16);
            v[6] = bf2f(ob[5] & 0xffffu); v[7] = bf2f(ob[5] >> 16);
            v[8] = bf2f(ob[6] & 0xffffu); v[9] = bf2f(ob[6] >> 16);
            float* obase = out + (size_t)batch * NC_ * S_ * S_;
            for (int dx = 0; dx < 2; ++dx) {
                int x_ = xi + dx; if (x_ >= S_) continue;
                float wx = dx ? rx : (1.0f - rx);
                for (int dy = 0; dy < 2; ++dy) {
                    int y_ = yi + dy; if (y_ >= S_) continue;
                    float w = wx * (dy ? ry : (1.0f - ry));
                    for (int cc = 0; cc < NC_; ++cc)
                        atomicAdd(obase + (size_t)cc * S_ * S_ + y_ * S_ + x_,
                                  w * v[cc]);
                }
            }
        }
        return;
    }
    int b = idx / 4032;
    int j = idx - b * 4032;
    int gx, gy;
    if (j < 2048) {                                  // vertical lines gx%32==0
        gx = (j >> 8) << 5;
        gy = j & 255;
    } else {                                         // horizontal, gx%32!=0
        int j2 = j - 2048;
        int row = j2 / 248, col = j2 - row * 248;
        gy = row << 5;
        gx = col + 1 + col / 31;                     // 0..247 -> 1..255 \ {32k}
    }

    int txs[2], lxs[2], nx = 0;
    bool bx = (gx & 31) == 0, by = (gy & 31) == 0;
    if (bx) {
        if (gx > 0) { txs[nx] = (gx >> 5) - 1; lxs[nx] = 32; ++nx; }
        txs[nx] = gx >> 5; lxs[nx] = 0; ++nx;
    } else { txs[0] = gx >> 5; lxs[0] = gx & 31; nx = 1; }
    int tys[2], lys[2], ny = 0;
    if (by) {
        if (gy > 0) { tys[ny] = (gy >> 5) - 1; lys[ny] = 32; ++ny; }
        tys[ny] = gy >> 5; lys[ny] = 0; ++ny;
    } else { tys[0] = gy >> 5; lys[0] = gy & 31; ny = 1; }

    float acc[NC_];
#pragma unroll
    for (int q = 0; q < NC_; ++q) acc[q] = 0.0f;
    for (int jj = 0; jj < ny; ++jj)
        for (int ii = 0; ii < nx; ++ii) {
            int g = (b << 6) + (tys[jj] << 3) + txs[ii];
            int p = lys[jj] * IW + lxs[ii];
            const float* bb = borderBuf + ((size_t)g * (IW * IW) + p) * NC_;
#pragma unroll
            for (int q = 0; q < NC_; ++q) acc[q] += bb[q];
        }
    float* ob = out + (size_t)b * NC_ * S_ * S_ + gy * S_ + gx;
#pragma unroll
    for (int q = 0; q < NC_; ++q) ob[(size_t)q * S_ * S_] = acc[q];
}

// ---- fallback: direct atomic scatter (any shape) ----
__global__ void __launch_bounds__(256)
scatter_cic_kernel(const float* __restrict__ points,
                   const float* __restrict__ values,
                   float* __restrict__ out, int N) {
    const int n = blockIdx.x * blockDim.x + threadIdx.x;
    const int b = blockIdx.y;
    if (n >= N) return;
    const float* pb = points + (size_t)b * 2 * N;
    const float px = (pb[n] + 0.5f) * (float)S_;
    const float py = (pb[(size_t)N + n] + 0.5f) * (float)S_;
    const float xf = floorf(px), yf = floorf(py);
    const float rx = px - xf, ry = py - yf;
    const int xi = (int)xf, yi = (int)yf;
    const float* vb = values + (size_t)b * NC_ * N + n;
    float v[NC_];
#pragma unroll
    for (int c = 0; c < NC_; ++c) v[c] = vb[(size_t)c * N];
    float* ob = out + (size_t)b * NC_ * S_ * S_;
#pragma unroll
    for (int dx = 0; dx < 2; ++dx) {
        const int x_ = xi + dx;
        if (x_ < 0 || x_ >= S_) continue;
        const float wx = dx ? rx : (1.0f - rx);
#pragma unroll
        for (int dy = 0; dy < 2; ++dy) {
            const int y_ = yi + dy;
            if (y_ < 0 || y_ >= S_) continue;
            const float w = wx * (dy ? ry : (1.0f - ry));
            const int idx = y_ * S_ + x_;
#pragma unroll
            for (int c = 0; c < NC_; ++c)
                atomicAdd(ob + (size_t)c * S_ * S_ + idx, w * v[c]);
        }
    }
}

extern "C" void kernel_launch(void* const* d_in, const int* in_sizes, int n_in,
                              void* d_out, int out_size, void* d_ws, size_t ws_size,
                              hipStream_t stream) {
    const float* points = (const float*)d_in[0];   // [B, 2, N]
    const float* values = (const float*)d_in[1];   // [B, NC, N]
    float* out = (float*)d_out;                    // [B, NC, S, S]

    const int B = out_size / (NC_ * S_ * S_);      // 16
    const int N = in_sizes[0] / (2 * B);           // 262144

    const size_t P = (size_t)B * N;
    const int blocksScatter = B * (N / (4 * WPTS)); // 2048 blocks
    const int nSlab = B * NBIN2;                   // 1024 tiles

    const size_t recBytes    = (size_t)nSlab * CAPR * 24;    // 113.2 MB slabs
    const size_t borderElems = (size_t)nSlab * (IW * IW) * NC_;
    const size_t ovfBytes    = P * 7 * 4;          // worst-case overflow list
    const size_t wsNeeded    = recBytes + (size_t)(nSlab + 1) * 4 +
                               borderElems * 4 + ovfBytes + 256;

    const bool fast = (N % (4 * WPTS) == 0) && (N >= 4 * WPTS) && (B > 0) &&
                      (P < (1u << 31) / 2) && (ws_size >= wsNeeded);

    if (fast) {
        char* w = (char*)d_ws;
        uint2* recsA     = (uint2*)w;
        u32* cursor      = (u32*)(w + recBytes);   // nSlab counters
        u32* ovfCnt      = cursor + nSlab;         // +1 overflow counter
        float* borderBuf = (float*)(ovfCnt + 1);
        u32* ovfBuf      = (u32*)(borderBuf + borderElems);

        hipMemsetAsync(cursor, 0, (size_t)(nSlab + 1) * 4, stream);
        k_scatter<<<blocksScatter, 256, 0, stream>>>(points, values, cursor,
                                                     ovfCnt, ovfBuf, recsA, N);
        k_fused<<<nSlab, 256, 0, stream>>>(recsA, cursor, out, borderBuf);
        const int borderTotal = B * 4032;
        k_border<<<(borderTotal + 255) / 256 + CLEAN_T / 256, 256, 0, stream>>>(
            borderBuf, out, ovfCnt, ovfBuf, borderTotal);
        // every output pixel is written by k_fused (interior) or k_border
    } else {
        hipMemsetAsync(d_out, 0, (size_t)out_size * sizeof(float), stream);
        dim3 block(256, 1, 1);
        dim3 grid((N + 255) / 256, B, 1);
        scatter_cic_kernel<<<grid, block, 0, stream>>>(points, values, out, N);
    }
}

// Round 8
// 355.609 us; speedup vs baseline: 1.0116x; 1.0116x over previous
//
#include <hip/hip_runtime.h>

// Problem constants: BOX=256, OS=1 -> S=256, NC=10, B=16, N=262144
#define S_     256
#define NC_    10
#define CHUNK  1024         // points per staging block
#define TS     32           // scatter tile size (32x32 px)
#define NBIN2  64           // 8x8 tiles of 32px per batch
#define CAPR   4608         // record slab per tile (mean 4096, +8 sigma)
#define NSLAB  1024         // B * NBIN2 (fixed-shape fast path)
#define PSTR   ((size_t)NSLAB * CAPR)   // SoA plane stride in records
#define IW     33           // LDS image width (32+1 for dx/dy=1 spill)
#define IMSZ   (NC_ * IW * IW)   // 10890 words = 43.6 KB
#define FPSCALE 262144.0f        // 2^18 fixed-point scale for LDS s32 accum
#define FPINV   (1.0f / 262144.0f)

typedef unsigned int u32;

__device__ __forceinline__ u32 f2bf(float f) {          // f32 -> bf16 (RNE)
    u32 u = __float_as_uint(f);
    return (u + 0x7fffu + ((u >> 16) & 1u)) >> 16;
}
__device__ __forceinline__ float bf2f(u32 h) { return __uint_as_float(h << 16); }

// Record (24 B) stored as 3 SoA uint2 PLANES (R7 lesson: five structural
// k_scatter variants all stuck at ~100-112us @ ~2TB/s effective with VALU/
// LDS/occupancy idle. Untested mechanism: AoS 24B-stride stores make every
// store instruction a 24-line partial-line scatter -> ~3x L2 write
// transactions. SoA planes make each store/load instruction 64x8B
// contiguous.) plane0=(w0: qx|qy<<16, w1: v0v1), plane1=(v2v3,v4v5),
// plane2=(v6v7,v8v9).
//
// R8 pipeline: memset(cursor) -> k_scatter (R5 block structure + SoA flush)
// -> k_fused (u32 ds_add fixed-point LDS image, SoA plane reads) -> k_border.

// ---- K3: in-LDS counting sort per chunk, then SoA coalesced flush ----
__global__ void __launch_bounds__(256)
k_scatter(const float* __restrict__ points, const float* __restrict__ values,
          u32* __restrict__ cursor, u32* __restrict__ ovfCnt,
          u32* __restrict__ ovfBuf, uint2* __restrict__ recs, int N) {
    __shared__ u32 cnt[NBIN2];          // histogram -> LDS sort cursor
    __shared__ u32 gOff[NBIN2];         // global slab base - excl
    __shared__ unsigned char binId[CHUNK];
    __shared__ u32 lw[6][CHUNK];        // 24 KB sorted record words (SoA)

    const int tid = threadIdx.x;
    const int cpb = N / CHUNK;
    const int b  = blockIdx.x / cpb;
    const int n0 = (blockIdx.x % cpb) * CHUNK;
    const float* pb = points + (size_t)b * 2 * N;
    const float* vb = values + (size_t)b * NC_ * N;
    const int nb = n0 + tid * 4;

    if (tid < NBIN2) cnt[tid] = 0;

    const float4 pxv = *(const float4*)(pb + nb);
    const float4 pyv = *(const float4*)(pb + (size_t)N + nb);
    float4 vv[NC_];
#pragma unroll
    for (int c = 0; c < NC_; ++c)
        vv[c] = *(const float4*)(vb + (size_t)c * N + nb);

    __syncthreads();                     // cnt zeroed

    // phase 1: quantize 4 points, per-block 64-bin histogram
    float px4[4] = {pxv.x, pxv.y, pxv.z, pxv.w};
    float py4[4] = {pyv.x, pyv.y, pyv.z, pyv.w};
    u32 w0[4], binA[4];
#pragma unroll
    for (int k = 0; k < 4; ++k) {
        float px = (px4[k] + 0.5f) * (float)S_;
        float py = (py4[k] + 0.5f) * (float)S_;
        int xi = (int)floorf(px), yi = (int)floorf(py);
        u32 qx = __float2uint_rn((px - (float)(xi & ~31)) * 2048.0f);
        u32 qy = __float2uint_rn((py - (float)(yi & ~31)) * 2048.0f);
        qx = min(qx, 65535u); qy = min(qy, 65535u);
        w0[k] = qx | (qy << 16);
        binA[k] = (u32)(((yi >> 5) << 3) + (xi >> 5));
        atomicAdd(&cnt[binA[k]], 1u);
    }
    __syncthreads();

    // phase 2: wave-0 shfl exclusive scan of 64 bins + global slab claim
    if (tid < NBIN2) {
        u32 myCnt = cnt[tid];
        u32 x = myCnt;
#pragma unroll
        for (int off = 1; off < 64; off <<= 1) {
            u32 y = __shfl_up(x, off, 64);
            if (tid >= off) x += y;
        }
        u32 excl = x - myCnt;
        u32 gt = (u32)b * NBIN2 + (u32)tid;
        u32 gbase = 0;
        if (myCnt) gbase = gt * (u32)CAPR + atomicAdd(&cursor[gt], myCnt);
        gOff[tid] = gbase - excl;
        cnt[tid] = excl;                 // becomes LDS sort cursor
    }
    __syncthreads();

    // phase 3: pack records, scatter into LDS in bin order
#pragma unroll
    for (int k = 0; k < 4; ++k) {
        u32 bin = binA[k];
        u32 slot = atomicAdd(&cnt[bin], 1u);
        binId[slot] = (unsigned char)bin;
#define VG(c) ((&vv[c].x)[k])
        lw[0][slot] = w0[k];
        lw[1][slot] = f2bf(VG(0)) | (f2bf(VG(1)) << 16);
        lw[2][slot] = f2bf(VG(2)) | (f2bf(VG(3)) << 16);
        lw[3][slot] = f2bf(VG(4)) | (f2bf(VG(5)) << 16);
        lw[4][slot] = f2bf(VG(6)) | (f2bf(VG(7)) << 16);
        lw[5][slot] = f2bf(VG(8)) | (f2bf(VG(9)) << 16);
#undef VG
    }
    __syncthreads();

    // phase 4: SoA coalesced flush. Each store instruction: 64 lanes x 8 B
    // contiguous within a run (vs AoS 24B-stride partial-line scatter).
    const u32 tb0 = (u32)b * NBIN2;
#pragma unroll
    for (int k = 0; k < 4; ++k) {
        u32 r = (u32)tid + (u32)k * 256;
        u32 bin = binId[r];
        u32 dst = gOff[bin] + r;
        u32 a0 = lw[0][r], a1 = lw[1][r], a2 = lw[2][r],
            a3 = lw[3][r], a4 = lw[4][r], a5 = lw[5][r];
        u32 rel = dst - (tb0 + bin) * (u32)CAPR;
        if (rel < (u32)CAPR) {           // true unless tile > CAPR records
            recs[dst]            = make_uint2(a0, a1);
            recs[PSTR + dst]     = make_uint2(a2, a3);
            recs[2 * PSTR + dst] = make_uint2(a4, a5);
        } else {                         // slab overflow -> side list (cold)
            u32 oi = atomicAdd(ovfCnt, 1u);
            u32* ob = ovfBuf + (size_t)oi * 7;
            ob[0] = tb0 + bin;
            ob[1] = a0; ob[2] = a1; ob[3] = a2;
            ob[4] = a3; ob[5] = a4; ob[6] = a5;
        }
    }
}

// ---- K4: LDS-image fixed-point deposit, one block per 32x32 tile ----
// Native ds_add_u32 (R4 lesson: f32 LDS atomicAdd = CAS loop, 8x slower).
// SoA plane reads: 3 coalesced uint2 streams. 2-deep register prefetch.
__global__ void __launch_bounds__(256)
k_fused(const uint2* __restrict__ recs, const u32* __restrict__ cursor,
        float* __restrict__ out, float* __restrict__ borderBuf) {
    __shared__ u32 img[IMSZ];           // 43.6 KB -> 3 blocks/CU

    const int tid = threadIdx.x;
    const int g = blockIdx.x;                       // batch*64 + tile
    const int batch = g >> 6, t = g & 63;
    const int ox = (t & 7) * TS, oy = (t >> 3) * TS;
    const u32 base = (u32)g * (u32)CAPR;            // fixed slab base
    const u32 n = min(cursor[g], (u32)CAPR);        // overflow -> k_border tail

    for (int p = tid; p < IMSZ; p += 256) img[p] = 0u;
    __syncthreads();

    u32 i = tid;
    uint2 a0, a1, a2;
    if (i < n) {
        a0 = recs[base + i];
        a1 = recs[PSTR + base + i];
        a2 = recs[2 * PSTR + base + i];
    }
    while (i < n) {
        u32 j = i + 256;
        uint2 b0, b1, b2;
        if (j < n) {                     // prefetch next record
            b0 = recs[base + j];
            b1 = recs[PSTR + base + j];
            b2 = recs[2 * PSTR + base + j];
        }
        u32 qx = a0.x & 0xffffu, qy = a0.x >> 16;
        int xi = (int)(qx >> 11), yi = (int)(qy >> 11);
        float rx = (float)(qx & 2047u) * (1.0f / 2048.0f);
        float ry = (float)(qy & 2047u) * (1.0f / 2048.0f);
        float w00 = (1.0f - rx) * (1.0f - ry) * FPSCALE;   // (xi,   yi  )
        float w10 = rx * (1.0f - ry) * FPSCALE;            // (xi+1, yi  )
        float w01 = (1.0f - rx) * ry * FPSCALE;            // (xi,   yi+1)
        float w11 = rx * ry * FPSCALE;                     // (xi+1, yi+1)
        int p00 = yi * IW + xi;
        float v[NC_];
        v[0] = bf2f(a0.y & 0xffffu); v[1] = bf2f(a0.y >> 16);
        v[2] = bf2f(a1.x & 0xffffu); v[3] = bf2f(a1.x >> 16);
        v[4] = bf2f(a1.y & 0xffffu); v[5] = bf2f(a1.y >> 16);
        v[6] = bf2f(a2.x & 0xffffu); v[7] = bf2f(a2.x >> 16);
        v[8] = bf2f(a2.y & 0xffffu); v[9] = bf2f(a2.y >> 16);
#pragma unroll
        for (int c = 0; c < NC_; ++c) {
            float vc = v[c];
            u32* ib = img + c * (IW * IW) + p00;  // c*IW*IW*4 = imm offset
            atomicAdd(ib,          (u32)__float2int_rn(w00 * vc));
            atomicAdd(ib + 1,      (u32)__float2int_rn(w10 * vc));
            atomicAdd(ib + IW,     (u32)__float2int_rn(w01 * vc));
            atomicAdd(ib + IW + 1, (u32)__float2int_rn(w11 * vc));
        }
        a0 = b0; a1 = b1; a2 = b2;
        i = j;
    }
    __syncthreads();

    // writeback: interior (lx,ly in 1..31) owned uniquely by this tile
    for (int p = tid; p < IW * IW; p += 256) {
        int lx = p % IW, ly = p / IW;
        bool interior = (lx >= 1) & (lx <= 31) & (ly >= 1) & (ly <= 31);
        if (interior) {
            int gx = ox + lx, gy = oy + ly;
            float* ob = out + (size_t)batch * NC_ * S_ * S_ + gy * S_ + gx;
#pragma unroll
            for (int q = 0; q < NC_; ++q)
                ob[(size_t)q * S_ * S_] =
                    (float)(int)img[q * (IW * IW) + p] * FPINV;
        } else {
            float* bb = borderBuf + ((size_t)g * (IW * IW) + p) * NC_;
#pragma unroll
            for (int q = 0; q < NC_; ++q)
                bb[q] = (float)(int)img[q * (IW * IW) + p] * FPINV;
        }
    }
}

// ---- K5: combine border partials; tail blocks process slab-overflow list ----
// Border px per batch: 8 cols x 256 + 8 rows x 248 = 4032.
#define CLEAN_T 4096                                 // 16 tail blocks
__global__ void __launch_bounds__(256)
k_border(const float* __restrict__ borderBuf, float* __restrict__ out,
         const u32* __restrict__ ovfCnt, const u32* __restrict__ ovfBuf,
         int total) {
    int idx = blockIdx.x * 256 + threadIdx.x;
    if (idx >= total) {
        // overflow-cleanup role (no-op unless a tile exceeded CAPR records)
        u32 oc = *ovfCnt;
        for (u32 j = (u32)(idx - total); j < oc; j += CLEAN_T) {
            const u32* ob = ovfBuf + (size_t)j * 7;
            u32 g = ob[0];
            int batch = (int)(g >> 6), t = (int)(g & 63u);
            int ox = (t & 7) * TS, oy = (t >> 3) * TS;
            u32 w0 = ob[1];
            u32 qx = w0 & 0xffffu, qy = w0 >> 16;
            int xi = ox + (int)(qx >> 11), yi = oy + (int)(qy >> 11);
            float rx = (float)(qx & 2047u) * (1.0f / 2048.0f);
            float ry = (float)(qy & 2047u) * (1.0f / 2048.0f);
            float v[NC_];
            v[0] = bf2f(ob[2] & 0xffffu); v[1] = bf2f(ob[2] >> 16);
            v[2] = bf2f(ob[3] & 0xffffu); v[3] = bf2f(ob[3] >> 16);
            v[4] = bf2f(ob[4] & 0xffffu); v[5] = bf2f(ob[4] >> 16);
            v[6] = bf2f(ob[5] & 0xffffu); v[7] = bf2f(ob[5] >> 16);
            v[8] = bf2f(ob[6] & 0xffffu); v[9] = bf2f(ob[6] >> 16);
            float* obase = out + (size_t)batch * NC_ * S_ * S_;
            for (int dx = 0; dx < 2; ++dx) {
                int x_ = xi + dx; if (x_ >= S_) continue;
                float wx = dx ? rx : (1.0f - rx);
                for (int dy = 0; dy < 2; ++dy) {
                    int y_ = yi + dy; if (y_ >= S_) continue;
                    float w = wx * (dy ? ry : (1.0f - ry));
                    for (int cc = 0; cc < NC_; ++cc)
                        atomicAdd(obase + (size_t)cc * S_ * S_ + y_ * S_ + x_,
                                  w * v[cc]);
                }
            }
        }
        return;
    }
    int b = idx / 4032;
    int j = idx - b * 4032;
    int gx, gy;
    if (j < 2048) {                                  // vertical lines gx%32==0
        gx = (j >> 8) << 5;
        gy = j & 255;
    } else {                                         // horizontal, gx%32!=0
        int j2 = j - 2048;
        int row = j2 / 248, col = j2 - row * 248;
        gy = row << 5;
        gx = col + 1 + col / 31;                     // 0..247 -> 1..255 \ {32k}
    }

    int txs[2], lxs[2], nx = 0;
    bool bx = (gx & 31) == 0, by = (gy & 31) == 0;
    if (bx) {
        if (gx > 0) { txs[nx] = (gx >> 5) - 1; lxs[nx] = 32; ++nx; }
        txs[nx] = gx >> 5; lxs[nx] = 0; ++nx;
    } else { txs[0] = gx >> 5; lxs[0] = gx & 31; nx = 1; }
    int tys[2], lys[2], ny = 0;
    if (by) {
        if (gy > 0) { tys[ny] = (gy >> 5) - 1; lys[ny] = 32; ++ny; }
        tys[ny] = gy >> 5; lys[ny] = 0; ++ny;
    } else { tys[0] = gy >> 5; lys[0] = gy & 31; ny = 1; }

    float acc[NC_];
#pragma unroll
    for (int q = 0; q < NC_; ++q) acc[q] = 0.0f;
    for (int jj = 0; jj < ny; ++jj)
        for (int ii = 0; ii < nx; ++ii) {
            int g = (b << 6) + (tys[jj] << 3) + txs[ii];
            int p = lys[jj] * IW + lxs[ii];
            const float* bb = borderBuf + ((size_t)g * (IW * IW) + p) * NC_;
#pragma unroll
            for (int q = 0; q < NC_; ++q) acc[q] += bb[q];
        }
    float* ob = out + (size_t)b * NC_ * S_ * S_ + gy * S_ + gx;
#pragma unroll
    for (int q = 0; q < NC_; ++q) ob[(size_t)q * S_ * S_] = acc[q];
}

// ---- fallback: direct atomic scatter (any shape) ----
__global__ void __launch_bounds__(256)
scatter_cic_kernel(const float* __restrict__ points,
                   const float* __restrict__ values,
                   float* __restrict__ out, int N) {
    const int n = blockIdx.x * blockDim.x + threadIdx.x;
    const int b = blockIdx.y;
    if (n >= N) return;
    const float* pb = points + (size_t)b * 2 * N;
    const float px = (pb[n] + 0.5f) * (float)S_;
    const float py = (pb[(size_t)N + n] + 0.5f) * (float)S_;
    const float xf = floorf(px), yf = floorf(py);
    const float rx = px - xf, ry = py - yf;
    const int xi = (int)xf, yi = (int)yf;
    const float* vb = values + (size_t)b * NC_ * N + n;
    float v[NC_];
#pragma unroll
    for (int c = 0; c < NC_; ++c) v[c] = vb[(size_t)c * N];
    float* ob = out + (size_t)b * NC_ * S_ * S_;
#pragma unroll
    for (int dx = 0; dx < 2; ++dx) {
        const int x_ = xi + dx;
        if (x_ < 0 || x_ >= S_) continue;
        const float wx = dx ? rx : (1.0f - rx);
#pragma unroll
        for (int dy = 0; dy < 2; ++dy) {
            const int y_ = yi + dy;
            if (y_ < 0 || y_ >= S_) continue;
            const float w = wx * (dy ? ry : (1.0f - ry));
            const int idx = y_ * S_ + x_;
#pragma unroll
            for (int c = 0; c < NC_; ++c)
                atomicAdd(ob + (size_t)c * S_ * S_ + idx, w * v[c]);
        }
    }
}

extern "C" void kernel_launch(void* const* d_in, const int* in_sizes, int n_in,
                              void* d_out, int out_size, void* d_ws, size_t ws_size,
                              hipStream_t stream) {
    const float* points = (const float*)d_in[0];   // [B, 2, N]
    const float* values = (const float*)d_in[1];   // [B, NC, N]
    float* out = (float*)d_out;                    // [B, NC, S, S]

    const int B = out_size / (NC_ * S_ * S_);      // 16
    const int N = in_sizes[0] / (2 * B);           // 262144

    const size_t P = (size_t)B * N;
    const int cpb = N / CHUNK;                     // 256
    const int chunksTotal = B * cpb;               // 4096 blocks
    const int nSlab = B * NBIN2;                   // 1024 tiles

    const size_t recBytes    = 3 * PSTR * 8;       // 113.2 MB SoA planes
    const size_t borderElems = (size_t)nSlab * (IW * IW) * NC_;
    const size_t ovfBytes    = P * 7 * 4;          // worst-case overflow list
    const size_t wsNeeded    = recBytes + (size_t)(nSlab + 1) * 4 +
                               borderElems * 4 + ovfBytes + 256;

    const bool fast = (N % CHUNK == 0) && (N >= CHUNK) && (B == 16) &&
                      (nSlab == NSLAB) && (P < (1u << 31) / 2) &&
                      (ws_size >= wsNeeded);

    if (fast) {
        char* w = (char*)d_ws;
        uint2* recsA     = (uint2*)w;              // 3 SoA planes
        u32* cursor      = (u32*)(w + recBytes);   // nSlab counters
        u32* ovfCnt      = cursor + nSlab;         // +1 overflow counter
        float* borderBuf = (float*)(ovfCnt + 1);
        u32* ovfBuf      = (u32*)(borderBuf + borderElems);

        hipMemsetAsync(cursor, 0, (size_t)(nSlab + 1) * 4, stream);
        k_scatter<<<chunksTotal, 256, 0, stream>>>(points, values, cursor,
                                                   ovfCnt, ovfBuf, recsA, N);
        k_fused<<<nSlab, 256, 0, stream>>>(recsA, cursor, out, borderBuf);
        const int borderTotal = B * 4032;
        k_border<<<(borderTotal + 255) / 256 + CLEAN_T / 256, 256, 0, stream>>>(
            borderBuf, out, ovfCnt, ovfBuf, borderTotal);
        // every output pixel is written by k_fused (interior) or k_border
    } else {
        hipMemsetAsync(d_out, 0, (size_t)out_size * sizeof(float), stream);
        dim3 block(256, 1, 1);
        dim3 grid((N + 255) / 256, B, 1);
        scatter_cic_kernel<<<grid, block, 0, stream>>>(points, values, out, N);
    }
}

// Round 9
// 353.742 us; speedup vs baseline: 1.0169x; 1.0053x over previous
//
#include <hip/hip_runtime.h>

// Problem constants: BOX=256, OS=1 -> S=256, NC=10, B=16, N=262144
#define S_     256
#define NC_    10
#define CHUNK  1024         // points per staging block
#define TS     32           // scatter tile size (32x32 px)
#define NBIN2  64           // 8x8 tiles of 32px per batch
#define CAPR   4608         // record slab per tile (mean 4096, +8 sigma)
#define NSLAB  1024         // B * NBIN2 (fixed-shape fast path)
#define PSTR   ((size_t)NSLAB * CAPR)   // SoA plane stride in records
#define IW     33           // LDS image width (32+1 for dx/dy=1 spill)
#define IMSZ   (NC_ * IW * IW)   // 10890 words = 43.6 KB
#define FPSCALE 262144.0f        // 2^18 fixed-point scale for LDS s32 accum
#define FPINV   (1.0f / 262144.0f)
#define FT     512          // k_fused threads per block

typedef unsigned int u32;

__device__ __forceinline__ u32 f2bf(float f) {          // f32 -> bf16 (RNE)
    u32 u = __float_as_uint(f);
    return (u + 0x7fffu + ((u >> 16) & 1u)) >> 16;
}
__device__ __forceinline__ float bf2f(u32 h) { return __uint_as_float(h << 16); }

// Record (24 B) stored as 3 SoA uint2 planes. plane0=(w0: qx|qy<<16, v0v1),
// plane1=(v2v3,v4v5), plane2=(v6v7,v8v9).
//
// R9 status: k_scatter is at its practical floor (~105us) — six structural
// variants (occupancy 18->56%, float4, 2-chunk pipeline, asm vmcnt, zero
// barriers, SoA flush) all land 100-112us with every profiled resource <35%.
// This round: k_fused at 512 threads (2x waves feeding the ds_add pipe) +
// non-temporal out stores (out is write-once; keep L2 for record planes).

// ---- K3: in-LDS counting sort per chunk, then SoA coalesced flush ----
__global__ void __launch_bounds__(256)
k_scatter(const float* __restrict__ points, const float* __restrict__ values,
          u32* __restrict__ cursor, u32* __restrict__ ovfCnt,
          u32* __restrict__ ovfBuf, uint2* __restrict__ recs, int N) {
    __shared__ u32 cnt[NBIN2];          // histogram -> LDS sort cursor
    __shared__ u32 gOff[NBIN2];         // global slab base - excl
    __shared__ unsigned char binId[CHUNK];
    __shared__ u32 lw[6][CHUNK];        // 24 KB sorted record words (SoA)

    const int tid = threadIdx.x;
    const int cpb = N / CHUNK;
    const int b  = blockIdx.x / cpb;
    const int n0 = (blockIdx.x % cpb) * CHUNK;
    const float* pb = points + (size_t)b * 2 * N;
    const float* vb = values + (size_t)b * NC_ * N;
    const int nb = n0 + tid * 4;

    if (tid < NBIN2) cnt[tid] = 0;

    const float4 pxv = *(const float4*)(pb + nb);
    const float4 pyv = *(const float4*)(pb + (size_t)N + nb);
    float4 vv[NC_];
#pragma unroll
    for (int c = 0; c < NC_; ++c)
        vv[c] = *(const float4*)(vb + (size_t)c * N + nb);

    __syncthreads();                     // cnt zeroed

    // phase 1: quantize 4 points, per-block 64-bin histogram
    float px4[4] = {pxv.x, pxv.y, pxv.z, pxv.w};
    float py4[4] = {pyv.x, pyv.y, pyv.z, pyv.w};
    u32 w0[4], binA[4];
#pragma unroll
    for (int k = 0; k < 4; ++k) {
        float px = (px4[k] + 0.5f) * (float)S_;
        float py = (py4[k] + 0.5f) * (float)S_;
        int xi = (int)floorf(px), yi = (int)floorf(py);
        u32 qx = __float2uint_rn((px - (float)(xi & ~31)) * 2048.0f);
        u32 qy = __float2uint_rn((py - (float)(yi & ~31)) * 2048.0f);
        qx = min(qx, 65535u); qy = min(qy, 65535u);
        w0[k] = qx | (qy << 16);
        binA[k] = (u32)(((yi >> 5) << 3) + (xi >> 5));
        atomicAdd(&cnt[binA[k]], 1u);
    }
    __syncthreads();

    // phase 2: wave-0 shfl exclusive scan of 64 bins + global slab claim
    if (tid < NBIN2) {
        u32 myCnt = cnt[tid];
        u32 x = myCnt;
#pragma unroll
        for (int off = 1; off < 64; off <<= 1) {
            u32 y = __shfl_up(x, off, 64);
            if (tid >= off) x += y;
        }
        u32 excl = x - myCnt;
        u32 gt = (u32)b * NBIN2 + (u32)tid;
        u32 gbase = 0;
        if (myCnt) gbase = gt * (u32)CAPR + atomicAdd(&cursor[gt], myCnt);
        gOff[tid] = gbase - excl;
        cnt[tid] = excl;                 // becomes LDS sort cursor
    }
    __syncthreads();

    // phase 3: pack records, scatter into LDS in bin order
#pragma unroll
    for (int k = 0; k < 4; ++k) {
        u32 bin = binA[k];
        u32 slot = atomicAdd(&cnt[bin], 1u);
        binId[slot] = (unsigned char)bin;
#define VG(c) ((&vv[c].x)[k])
        lw[0][slot] = w0[k];
        lw[1][slot] = f2bf(VG(0)) | (f2bf(VG(1)) << 16);
        lw[2][slot] = f2bf(VG(2)) | (f2bf(VG(3)) << 16);
        lw[3][slot] = f2bf(VG(4)) | (f2bf(VG(5)) << 16);
        lw[4][slot] = f2bf(VG(6)) | (f2bf(VG(7)) << 16);
        lw[5][slot] = f2bf(VG(8)) | (f2bf(VG(9)) << 16);
#undef VG
    }
    __syncthreads();

    // phase 4: SoA coalesced flush
    const u32 tb0 = (u32)b * NBIN2;
#pragma unroll
    for (int k = 0; k < 4; ++k) {
        u32 r = (u32)tid + (u32)k * 256;
        u32 bin = binId[r];
        u32 dst = gOff[bin] + r;
        u32 a0 = lw[0][r], a1 = lw[1][r], a2 = lw[2][r],
            a3 = lw[3][r], a4 = lw[4][r], a5 = lw[5][r];
        u32 rel = dst - (tb0 + bin) * (u32)CAPR;
        if (rel < (u32)CAPR) {           // true unless tile > CAPR records
            recs[dst]            = make_uint2(a0, a1);
            recs[PSTR + dst]     = make_uint2(a2, a3);
            recs[2 * PSTR + dst] = make_uint2(a4, a5);
        } else {                         // slab overflow -> side list (cold)
            u32 oi = atomicAdd(ovfCnt, 1u);
            u32* ob = ovfBuf + (size_t)oi * 7;
            ob[0] = tb0 + bin;
            ob[1] = a0; ob[2] = a1; ob[3] = a2;
            ob[4] = a3; ob[5] = a4; ob[6] = a5;
        }
    }
}

// ---- K4: LDS-image fixed-point deposit, one block per 32x32 tile ----
// 512 threads: 3 blocks/CU (LDS-bound) now carry 24 waves/CU feeding the
// ds_add pipe; per-block wall halves. Native ds_add_u32 (R4 lesson: f32 LDS
// atomicAdd = CAS loop). NT stores: out is write-once, keep L2 for records.
__global__ void __launch_bounds__(FT)
k_fused(const uint2* __restrict__ recs, const u32* __restrict__ cursor,
        float* __restrict__ out, float* __restrict__ borderBuf) {
    __shared__ u32 img[IMSZ];           // 43.6 KB -> 3 blocks/CU

    const int tid = threadIdx.x;
    const int g = blockIdx.x;                       // batch*64 + tile
    const int batch = g >> 6, t = g & 63;
    const int ox = (t & 7) * TS, oy = (t >> 3) * TS;
    const u32 base = (u32)g * (u32)CAPR;            // fixed slab base
    const u32 n = min(cursor[g], (u32)CAPR);        // overflow -> k_border tail

    for (int p = tid; p < IMSZ; p += FT) img[p] = 0u;
    __syncthreads();

    u32 i = tid;
    uint2 a0, a1, a2;
    if (i < n) {
        a0 = recs[base + i];
        a1 = recs[PSTR + base + i];
        a2 = recs[2 * PSTR + base + i];
    }
    while (i < n) {
        u32 j = i + FT;
        uint2 b0, b1, b2;
        if (j < n) {                     // prefetch next record
            b0 = recs[base + j];
            b1 = recs[PSTR + base + j];
            b2 = recs[2 * PSTR + base + j];
        }
        u32 qx = a0.x & 0xffffu, qy = a0.x >> 16;
        int xi = (int)(qx >> 11), yi = (int)(qy >> 11);
        float rx = (float)(qx & 2047u) * (1.0f / 2048.0f);
        float ry = (float)(qy & 2047u) * (1.0f / 2048.0f);
        float w00 = (1.0f - rx) * (1.0f - ry) * FPSCALE;   // (xi,   yi  )
        float w10 = rx * (1.0f - ry) * FPSCALE;            // (xi+1, yi  )
        float w01 = (1.0f - rx) * ry * FPSCALE;            // (xi,   yi+1)
        float w11 = rx * ry * FPSCALE;                     // (xi+1, yi+1)
        int p00 = yi * IW + xi;
        float v[NC_];
        v[0] = bf2f(a0.y & 0xffffu); v[1] = bf2f(a0.y >> 16);
        v[2] = bf2f(a1.x & 0xffffu); v[3] = bf2f(a1.x >> 16);
        v[4] = bf2f(a1.y & 0xffffu); v[5] = bf2f(a1.y >> 16);
        v[6] = bf2f(a2.x & 0xffffu); v[7] = bf2f(a2.x >> 16);
        v[8] = bf2f(a2.y & 0xffffu); v[9] = bf2f(a2.y >> 16);
#pragma unroll
        for (int c = 0; c < NC_; ++c) {
            float vc = v[c];
            u32* ib = img + c * (IW * IW) + p00;  // c*IW*IW*4 = imm offset
            atomicAdd(ib,          (u32)__float2int_rn(w00 * vc));
            atomicAdd(ib + 1,      (u32)__float2int_rn(w10 * vc));
            atomicAdd(ib + IW,     (u32)__float2int_rn(w01 * vc));
            atomicAdd(ib + IW + 1, (u32)__float2int_rn(w11 * vc));
        }
        a0 = b0; a1 = b1; a2 = b2;
        i = j;
    }
    __syncthreads();

    // writeback: interior (lx,ly in 1..31) owned uniquely by this tile
    for (int p = tid; p < IW * IW; p += FT) {
        int lx = p % IW, ly = p / IW;
        bool interior = (lx >= 1) & (lx <= 31) & (ly >= 1) & (ly <= 31);
        if (interior) {
            int gx = ox + lx, gy = oy + ly;
            float* ob = out + (size_t)batch * NC_ * S_ * S_ + gy * S_ + gx;
#pragma unroll
            for (int q = 0; q < NC_; ++q)
                __builtin_nontemporal_store(
                    (float)(int)img[q * (IW * IW) + p] * FPINV,
                    ob + (size_t)q * S_ * S_);
        } else {
            float* bb = borderBuf + ((size_t)g * (IW * IW) + p) * NC_;
#pragma unroll
            for (int q = 0; q < NC_; ++q)
                bb[q] = (float)(int)img[q * (IW * IW) + p] * FPINV;
        }
    }
}

// ---- K5: combine border partials; tail blocks process slab-overflow list ----
// Border px per batch: 8 cols x 256 + 8 rows x 248 = 4032.
#define CLEAN_T 4096                                 // 16 tail blocks
__global__ void __launch_bounds__(256)
k_border(const float* __restrict__ borderBuf, float* __restrict__ out,
         const u32* __restrict__ ovfCnt, const u32* __restrict__ ovfBuf,
         int total) {
    int idx = blockIdx.x * 256 + threadIdx.x;
    if (idx >= total) {
        // overflow-cleanup role (no-op unless a tile exceeded CAPR records)
        u32 oc = *ovfCnt;
        for (u32 j = (u32)(idx - total); j < oc; j += CLEAN_T) {
            const u32* ob = ovfBuf + (size_t)j * 7;
            u32 g = ob[0];
            int batch = (int)(g >> 6), t = (int)(g & 63u);
            int ox = (t & 7) * TS, oy = (t >> 3) * TS;
            u32 w0 = ob[1];
            u32 qx = w0 & 0xffffu, qy = w0 >> 16;
            int xi = ox + (int)(qx >> 11), yi = oy + (int)(qy >> 11);
            float rx = (float)(qx & 2047u) * (1.0f / 2048.0f);
            float ry = (float)(qy & 2047u) * (1.0f / 2048.0f);
            float v[NC_];
            v[0] = bf2f(ob[2] & 0xffffu); v[1] = bf2f(ob[2] >> 16);
            v[2] = bf2f(ob[3] & 0xffffu); v[3] = bf2f(ob[3] >> 16);
            v[4] = bf2f(ob[4] & 0xffffu); v[5] = bf2f(ob[4] >> 16);
            v[6] = bf2f(ob[5] & 0xffffu); v[7] = bf2f(ob[5] >> 16);
            v[8] = bf2f(ob[6] & 0xffffu); v[9] = bf2f(ob[6] >> 16);
            float* obase = out + (size_t)batch * NC_ * S_ * S_;
            for (int dx = 0; dx < 2; ++dx) {
                int x_ = xi + dx; if (x_ >= S_) continue;
                float wx = dx ? rx : (1.0f - rx);
                for (int dy = 0; dy < 2; ++dy) {
                    int y_ = yi + dy; if (y_ >= S_) continue;
                    float w = wx * (dy ? ry : (1.0f - ry));
                    for (int cc = 0; cc < NC_; ++cc)
                        atomicAdd(obase + (size_t)cc * S_ * S_ + y_ * S_ + x_,
                                  w * v[cc]);
                }
            }
        }
        return;
    }
    int b = idx / 4032;
    int j = idx - b * 4032;
    int gx, gy;
    if (j < 2048) {                                  // vertical lines gx%32==0
        gx = (j >> 8) << 5;
        gy = j & 255;
    } else {                                         // horizontal, gx%32!=0
        int j2 = j - 2048;
        int row = j2 / 248, col = j2 - row * 248;
        gy = row << 5;
        gx = col + 1 + col / 31;                     // 0..247 -> 1..255 \ {32k}
    }

    int txs[2], lxs[2], nx = 0;
    bool bx = (gx & 31) == 0, by = (gy & 31) == 0;
    if (bx) {
        if (gx > 0) { txs[nx] = (gx >> 5) - 1; lxs[nx] = 32; ++nx; }
        txs[nx] = gx >> 5; lxs[nx] = 0; ++nx;
    } else { txs[0] = gx >> 5; lxs[0] = gx & 31; nx = 1; }
    int tys[2], lys[2], ny = 0;
    if (by) {
        if (gy > 0) { tys[ny] = (gy >> 5) - 1; lys[ny] = 32; ++ny; }
        tys[ny] = gy >> 5; lys[ny] = 0; ++ny;
    } else { tys[0] = gy >> 5; lys[0] = gy & 31; ny = 1; }

    float acc[NC_];
#pragma unroll
    for (int q = 0; q < NC_; ++q) acc[q] = 0.0f;
    for (int jj = 0; jj < ny; ++jj)
        for (int ii = 0; ii < nx; ++ii) {
            int g = (b << 6) + (tys[jj] << 3) + txs[ii];
            int p = lys[jj] * IW + lxs[ii];
            const float* bb = borderBuf + ((size_t)g * (IW * IW) + p) * NC_;
#pragma unroll
            for (int q = 0; q < NC_; ++q) acc[q] += bb[q];
        }
    float* ob = out + (size_t)b * NC_ * S_ * S_ + gy * S_ + gx;
#pragma unroll
    for (int q = 0; q < NC_; ++q)
        __builtin_nontemporal_store(acc[q], ob + (size_t)q * S_ * S_);
}

// ---- fallback: direct atomic scatter (any shape) ----
__global__ void __launch_bounds__(256)
scatter_cic_kernel(const float* __restrict__ points,
                   const float* __restrict__ values,
                   float* __restrict__ out, int N) {
    const int n = blockIdx.x * blockDim.x + threadIdx.x;
    const int b = blockIdx.y;
    if (n >= N) return;
    const float* pb = points + (size_t)b * 2 * N;
    const float px = (pb[n] + 0.5f) * (float)S_;
    const float py = (pb[(size_t)N + n] + 0.5f) * (float)S_;
    const float xf = floorf(px), yf = floorf(py);
    const float rx = px - xf, ry = py - yf;
    const int xi = (int)xf, yi = (int)yf;
    const float* vb = values + (size_t)b * NC_ * N + n;
    float v[NC_];
#pragma unroll
    for (int c = 0; c < NC_; ++c) v[c] = vb[(size_t)c * N];
    float* ob = out + (size_t)b * NC_ * S_ * S_;
#pragma unroll
    for (int dx = 0; dx < 2; ++dx) {
        const int x_ = xi + dx;
        if (x_ < 0 || x_ >= S_) continue;
        const float wx = dx ? rx : (1.0f - rx);
#pragma unroll
        for (int dy = 0; dy < 2; ++dy) {
            const int y_ = yi + dy;
            if (y_ < 0 || y_ >= S_) continue;
            const float w = wx * (dy ? ry : (1.0f - ry));
            const int idx = y_ * S_ + x_;
#pragma unroll
            for (int c = 0; c < NC_; ++c)
                atomicAdd(ob + (size_t)c * S_ * S_ + idx, w * v[c]);
        }
    }
}

extern "C" void kernel_launch(void* const* d_in, const int* in_sizes, int n_in,
                              void* d_out, int out_size, void* d_ws, size_t ws_size,
                              hipStream_t stream) {
    const float* points = (const float*)d_in[0];   // [B, 2, N]
    const float* values = (const float*)d_in[1];   // [B, NC, N]
    float* out = (float*)d_out;                    // [B, NC, S, S]

    const int B = out_size / (NC_ * S_ * S_);      // 16
    const int N = in_sizes[0] / (2 * B);           // 262144

    const size_t P = (size_t)B * N;
    const int cpb = N / CHUNK;                     // 256
    const int chunksTotal = B * cpb;               // 4096 blocks
    const int nSlab = B * NBIN2;                   // 1024 tiles

    const size_t recBytes    = 3 * PSTR * 8;       // 113.2 MB SoA planes
    const size_t borderElems = (size_t)nSlab * (IW * IW) * NC_;
    const size_t ovfBytes    = P * 7 * 4;          // worst-case overflow list
    const size_t wsNeeded    = recBytes + (size_t)(nSlab + 1) * 4 +
                               borderElems * 4 + ovfBytes + 256;

    const bool fast = (N % CHUNK == 0) && (N >= CHUNK) && (B == 16) &&
                      (nSlab == NSLAB) && (P < (1u << 31) / 2) &&
                      (ws_size >= wsNeeded);

    if (fast) {
        char* w = (char*)d_ws;
        uint2* recsA     = (uint2*)w;              // 3 SoA planes
        u32* cursor      = (u32*)(w + recBytes);   // nSlab counters
        u32* ovfCnt      = cursor + nSlab;         // +1 overflow counter
        float* borderBuf = (float*)(ovfCnt + 1);
        u32* ovfBuf      = (u32*)(borderBuf + borderElems);

        hipMemsetAsync(cursor, 0, (size_t)(nSlab + 1) * 4, stream);
        k_scatter<<<chunksTotal, 256, 0, stream>>>(points, values, cursor,
                                                   ovfCnt, ovfBuf, recsA, N);
        k_fused<<<nSlab, FT, 0, stream>>>(recsA, cursor, out, borderBuf);
        const int borderTotal = B * 4032;
        k_border<<<(borderTotal + 255) / 256 + CLEAN_T / 256, 256, 0, stream>>>(
            borderBuf, out, ovfCnt, ovfBuf, borderTotal);
        // every output pixel is written by k_fused (interior) or k_border
    } else {
        hipMemsetAsync(d_out, 0, (size_t)out_size * sizeof(float), stream);
        dim3 block(256, 1, 1);
        dim3 grid((N + 255) / 256, B, 1);
        scatter_cic_kernel<<<grid, block, 0, stream>>>(points, values, out, N);
    }
}